// Round 3
// baseline (76.006 us; speedup 1.0000x reference)
//
#include <hip/hip_runtime.h>

// Single fused kernel.
// Phase 1 (wave 0 of every block, redundantly): build the fixed post-encoding
// 8x8 unitary U with one complex entry per lane (lane = row*8 + col), gates as
// shuffle butterflies; reduce to M = Re(U^dag Z0 U); contract to the 27
// trilinear coefficients  z = sum B[a][b][g] * g0_a * g1_b * g2_g,
// gi = (1, cos x_i, sin x_i).  Weights are 72 B, L2-cached: redundant
// per-block compute is cheaper than a serialized precompute launch.
// Phase 2 (all threads): evaluate 4 samples each; loads are issued BEFORE the
// coeffs compute so the memory latency hides it.
__global__ __launch_bounds__(256) void vqc_fused_kernel(
    const float* __restrict__ in, const float* __restrict__ w,
    float* __restrict__ out, int B) {
    __shared__ float LUr[64], LUi[64], LM[64];
    __shared__ float Bs[27];

    const int t = threadIdx.x;
    const int base = blockIdx.x * 1024 + t;   // 256 threads x 4 samples

    // Issue all input loads first (cols 0..3 of each 8-col row).
    float4 v[4];
#pragma unroll
    for (int k = 0; k < 4; ++k) {
        const int b = base + k * 256;
        if (b < B) v[k] = reinterpret_cast<const float4*>(in)[2 * b];
    }

    // ---- Phase 1: coefficients (wave 0 only) ----
    if (t < 64) {
        const int lane = t;
        const int i = lane >> 3;               // row (amplitude index)
        float vr = (i == (lane & 7)) ? 1.f : 0.f;  // U = I
        float vi = 0.f;

#pragma unroll
        for (int l = 0; l < 3; ++l) {
#pragma unroll
            for (int q = 0; q < 3; ++q) {
                const int m = 4 >> q;          // row-bit for qubit q
                const int d = m << 3;          // lane xor distance
                // RY
                {
                    float th = 0.5f * w[(l * 3 + q) * 2 + 0];
                    float s, c;
                    __sincosf(th, &s, &c);
                    float pr = __shfl_xor(vr, d, 64);
                    float pi = __shfl_xor(vi, d, 64);
                    float sgn = (i & m) ? s : -s;
                    vr = c * vr + sgn * pr;
                    vi = c * vi + sgn * pi;
                }
                // RZ: multiply by (cz, +-sz)
                {
                    float ph = 0.5f * w[(l * 3 + q) * 2 + 1];
                    float sz, cz;
                    __sincosf(ph, &sz, &cz);
                    float ei = (i & m) ? sz : -sz;
                    float nr = cz * vr - ei * vi;
                    float ni = cz * vi + ei * vr;
                    vr = nr; vi = ni;
                }
            }
            // CNOT01: rows 4<->6, 5<->7 (lane xor 16 when i&4)
            {
                float pr = __shfl_xor(vr, 16, 64);
                float pi = __shfl_xor(vi, 16, 64);
                if (i & 4) { vr = pr; vi = pi; }
            }
            // CNOT12: rows 2<->3, 6<->7 (lane xor 8 when i&2)
            {
                float pr = __shfl_xor(vr, 8, 64);
                float pi = __shfl_xor(vi, 8, 64);
                if (i & 2) { vr = pr; vi = pi; }
            }
        }
        LUr[lane] = vr; LUi[lane] = vi;
    }
    __syncthreads();

    if (t < 64) {
        // lane = j*8+k: M[j][k] = sum_i sign_i * Re(conj(U[i][j])*U[i][k])
        const int jj = t >> 3, kk = t & 7;
        float acc = 0.f;
#pragma unroll
        for (int ii = 0; ii < 8; ++ii) {
            float s = LUr[ii * 8 + jj] * LUr[ii * 8 + kk] +
                      LUi[ii * 8 + jj] * LUi[ii * 8 + kk];
            acc += (ii < 4) ? s : -s;
        }
        LM[t] = acc;
    }
    __syncthreads();

    if (t == 0) {
        float M[8][8];
#pragma unroll
        for (int a = 0; a < 8; ++a)
#pragma unroll
            for (int b = 0; b < 8; ++b) M[a][b] = LM[a * 8 + b];

        // Contract qubit-0: c^2=(1+cos)/2, s^2=(1-cos)/2, cs=sin/2
        float T1[3][4][4];
#pragma unroll
        for (int jl = 0; jl < 4; ++jl)
#pragma unroll
            for (int kl = 0; kl < 4; ++kl) {
                T1[0][jl][kl] = 0.5f * (M[jl][kl] + M[4 + jl][4 + kl]);
                T1[1][jl][kl] = 0.5f * (M[jl][kl] - M[4 + jl][4 + kl]);
                T1[2][jl][kl] = 0.5f * (M[jl][4 + kl] + M[4 + jl][kl]);
            }
        // Contract qubit-1
        float T2[3][3][2][2];
#pragma unroll
        for (int a = 0; a < 3; ++a)
#pragma unroll
            for (int c = 0; c < 2; ++c)
#pragma unroll
                for (int cp = 0; cp < 2; ++cp) {
                    T2[a][0][c][cp] = 0.5f * (T1[a][c][cp] + T1[a][2 + c][2 + cp]);
                    T2[a][1][c][cp] = 0.5f * (T1[a][c][cp] - T1[a][2 + c][2 + cp]);
                    T2[a][2][c][cp] = 0.5f * (T1[a][c][2 + cp] + T1[a][2 + c][cp]);
                }
        // Contract qubit-2 -> 27 coefficients
#pragma unroll
        for (int a = 0; a < 3; ++a)
#pragma unroll
            for (int b = 0; b < 3; ++b) {
                Bs[(a * 3 + b) * 3 + 0] = 0.5f * (T2[a][b][0][0] + T2[a][b][1][1]);
                Bs[(a * 3 + b) * 3 + 1] = 0.5f * (T2[a][b][0][0] - T2[a][b][1][1]);
                Bs[(a * 3 + b) * 3 + 2] = 0.5f * (T2[a][b][0][1] + T2[a][b][1][0]);
            }
    }
    __syncthreads();

    // ---- Phase 2: evaluate 4 samples (LDS broadcast reads, conflict-free) ----
#pragma unroll
    for (int k = 0; k < 4; ++k) {
        const int b = base + k * 256;
        if (b >= B) continue;
        float s0, c0, s1, c1, s2, c2;
        __sincosf(v[k].x, &s0, &c0);
        __sincosf(v[k].y, &s1, &c1);
        __sincosf(v[k].z, &s2, &c2);

        float e0 = 0.f, e1 = 0.f, e2 = 0.f;
#pragma unroll
        for (int a = 0; a < 3; ++a) {
            float h0 = Bs[(a * 3 + 0) * 3 + 0] + Bs[(a * 3 + 0) * 3 + 1] * c2 + Bs[(a * 3 + 0) * 3 + 2] * s2;
            float h1 = Bs[(a * 3 + 1) * 3 + 0] + Bs[(a * 3 + 1) * 3 + 1] * c2 + Bs[(a * 3 + 1) * 3 + 2] * s2;
            float h2 = Bs[(a * 3 + 2) * 3 + 0] + Bs[(a * 3 + 2) * 3 + 1] * c2 + Bs[(a * 3 + 2) * 3 + 2] * s2;
            float ea = h0 + h1 * c1 + h2 * s1;
            if (a == 0) e0 = ea; else if (a == 1) e1 = ea; else e2 = ea;
        }
        out[b] = e0 + e1 * c0 + e2 * s0;
    }
}

extern "C" void kernel_launch(void* const* d_in, const int* in_sizes, int n_in,
                              void* d_out, int out_size, void* d_ws, size_t ws_size,
                              hipStream_t stream) {
    const float* inputs = (const float*)d_in[0];   // (B, 8) float32
    const float* qw     = (const float*)d_in[1];   // (3, 3, 2) float32
    float* out          = (float*)d_out;           // (B, 1) float32

    const int B = in_sizes[0] / 8;
    const int blocks = (B + 1023) / 1024;          // 4 samples/thread
    vqc_fused_kernel<<<blocks, 256, 0, stream>>>(inputs, qw, out, B);
}